// Round 3
// baseline (178.458 us; speedup 1.0000x reference)
//
#include <hip/hip_runtime.h>
#include <math.h>

#define NN   20000
#define NE   320000
#define FIN  128
#define FHID 256
#define FOUT 64
#define CLDS 264   // padded phase-2 LDS row stride (264 % 32 = 8 -> conflict-free 4-row reads)

// ---------- CSR build ----------
__global__ void k_init(float* deg, int* cnt) {
    int i = blockIdx.x * blockDim.x + threadIdx.x;
    if (i < NN) { deg[i] = 1.0f; cnt[i] = 0; }   // self-loop weight 1.0 pre-added
}

__global__ void k_deg(const int* __restrict__ dst, const float* __restrict__ ew,
                      float* __restrict__ deg, int* __restrict__ cnt) {
    int e = blockIdx.x * blockDim.x + threadIdx.x;
    if (e < NE) {
        int d = dst[e];
        atomicAdd(&deg[d], ew[e]);
        atomicAdd(&cnt[d], 1);
    }
}

// multi-block scan, stage 1: per-block inclusive scan of cnt; also computes dinv
__global__ __launch_bounds__(1024) void k_scan1(
    const int* __restrict__ cnt, const float* __restrict__ deg,
    float* __restrict__ dinv, int* __restrict__ off, int* __restrict__ bsum) {
    __shared__ int wsum[16];
    int tid = threadIdx.x, lane = tid & 63, w = tid >> 6;
    int i = blockIdx.x * 1024 + tid;
    int v = (i < NN) ? cnt[i] : 0;
    if (i < NN) {
        float dg = deg[i];
        dinv[i] = dg > 0.0f ? rsqrtf(dg) : 0.0f;
    }
    int sc = v;
    #pragma unroll
    for (int d = 1; d < 64; d <<= 1) {
        int t = __shfl_up(sc, d, 64);
        if (lane >= d) sc += t;
    }
    if (lane == 63) wsum[w] = sc;
    __syncthreads();
    if (w == 0) {
        int ws_ = (lane < 16) ? wsum[lane] : 0;
        #pragma unroll
        for (int d = 1; d < 16; d <<= 1) {
            int t = __shfl_up(ws_, d, 64);
            if (lane >= d) ws_ += t;
        }
        if (lane < 16) wsum[lane] = ws_;
    }
    __syncthreads();
    int inc = sc + (w ? wsum[w - 1] : 0);
    if (i < NN) off[i + 1] = inc;
    if (tid == 1023) bsum[blockIdx.x] = inc;
}

// stage 2: exclusive scan of the 20 block sums (single wave)
__global__ void k_scan2(int* bsum) {
    int l = threadIdx.x;
    int v = (l < 20) ? bsum[l] : 0;
    int sc = v;
    #pragma unroll
    for (int d = 1; d < 32; d <<= 1) {
        int t = __shfl_up(sc, d, 64);
        if (l >= d) sc += t;
    }
    if (l < 20) bsum[l] = sc - v;
}

// stage 3: add block prefix; zero cnt for scatter
__global__ __launch_bounds__(1024) void k_scan3(int* __restrict__ off,
                                                const int* __restrict__ bsum,
                                                int* __restrict__ cnt) {
    int i = blockIdx.x * 1024 + threadIdx.x;
    if (i < NN) { off[i + 1] += bsum[blockIdx.x]; cnt[i] = 0; }
    if (i == 0) off[0] = 0;
}

// scatter with fully-precomputed coefficient: coef = ew * dinv[s] * dinv[d]
__global__ void k_scatter(const int* __restrict__ src, const int* __restrict__ dst,
                          const float* __restrict__ ew, const float* __restrict__ dinv,
                          const int* __restrict__ off, int* __restrict__ cnt,
                          int2* __restrict__ ep) {
    int e = blockIdx.x * blockDim.x + threadIdx.x;
    if (e < NE) {
        int d = dst[e], s = src[e];
        float c = ew[e] * dinv[s] * dinv[d];
        int p = off[d] + atomicAdd(&cnt[d], 1);
        ep[p] = make_int2(s, __float_as_int(c));
    }
}

// ---------- layer-1 aggregate: A = S @ X. half-wave (32 lanes x float4) per node ----------
__global__ __launch_bounds__(256) void k_aggx(
    const float* __restrict__ x, const int2* __restrict__ ep,
    const float* __restrict__ dinv, const int* __restrict__ off,
    float* __restrict__ A) {
    int half = threadIdx.x >> 5, l = threadIdx.x & 31;
    int n = (blockIdx.x << 3) + half;
    const float* xc = x + (l << 2);
    float ax = 0.f, ay = 0.f, az = 0.f, aw = 0.f;
    int p = off[n], p1 = off[n + 1];
    for (; p + 4 <= p1; p += 4) {
        int2 e0 = ep[p], e1 = ep[p + 1], e2 = ep[p + 2], e3 = ep[p + 3];
        float4 v0 = *(const float4*)(xc + ((size_t)e0.x << 7));
        float4 v1 = *(const float4*)(xc + ((size_t)e1.x << 7));
        float4 v2 = *(const float4*)(xc + ((size_t)e2.x << 7));
        float4 v3 = *(const float4*)(xc + ((size_t)e3.x << 7));
        float c0 = __int_as_float(e0.y), c1 = __int_as_float(e1.y);
        float c2 = __int_as_float(e2.y), c3 = __int_as_float(e3.y);
        ax += c0 * v0.x + c1 * v1.x + c2 * v2.x + c3 * v3.x;
        ay += c0 * v0.y + c1 * v1.y + c2 * v2.y + c3 * v3.y;
        az += c0 * v0.z + c1 * v1.z + c2 * v2.z + c3 * v3.z;
        aw += c0 * v0.w + c1 * v1.w + c2 * v2.w + c3 * v3.w;
    }
    for (; p < p1; ++p) {
        int2 e = ep[p];
        float4 v = *(const float4*)(xc + ((size_t)e.x << 7));
        float c = __int_as_float(e.y);
        ax += c * v.x; ay += c * v.y; az += c * v.z; aw += c * v.w;
    }
    float dn = dinv[n];
    float s2 = dn * dn;
    float4 xv = *(const float4*)(xc + ((size_t)n << 7));
    ax += s2 * xv.x; ay += s2 * xv.y; az += s2 * xv.z; aw += s2 * xv.w;
    *(float4*)(A + ((size_t)n << 7) + (l << 2)) = make_float4(ax, ay, az, aw);
}

// ---------- fused MLP: G = relu(A@W1+b1)@W2, 16 rows/block ----------
#define FMA8(J, AV, W0, W1V)                                              \
    acc[J][0] += (AV) * (W0).x; acc[J][1] += (AV) * (W0).y;               \
    acc[J][2] += (AV) * (W0).z; acc[J][3] += (AV) * (W0).w;               \
    acc[J][4] += (AV) * (W1V).x; acc[J][5] += (AV) * (W1V).y;             \
    acc[J][6] += (AV) * (W1V).z; acc[J][7] += (AV) * (W1V).w;

__global__ __launch_bounds__(256) void k_mlp(
    const float* __restrict__ A, const float* __restrict__ W1,
    const float* __restrict__ b1, const float* __restrict__ W2,
    float* __restrict__ G) {
    __shared__ float ldsA[16 * FIN];     // 8 KB
    __shared__ float ldsC[16 * CLDS];    // 16.5 KB
    int tid = threadIdx.x;
    int row0 = blockIdx.x * 16;

    // stage A tile (16 x 128) coalesced
    {
        const float4* Af = (const float4*)(A + (size_t)row0 * FIN);
        float4* Lf = (float4*)ldsA;
        Lf[tid] = Af[tid];
        Lf[tid + 256] = Af[tid + 256];
    }
    __syncthreads();

    // phase 1: C(16x256) = relu(As @ W1 + b1). thread = 8 cols x 2 rows
    int cg = tid & 31, rg = tid >> 5;
    int c0 = cg * 8, r0 = rg * 2;
    float acc[2][8] = {};
    for (int k = 0; k < FIN; k += 4) {
        float4 a0 = *(const float4*)&ldsA[(r0 + 0) * FIN + k];
        float4 a1 = *(const float4*)&ldsA[(r0 + 1) * FIN + k];
        #pragma unroll
        for (int kk = 0; kk < 4; ++kk) {
            float4 w0 = *(const float4*)&W1[(size_t)(k + kk) * FHID + c0];
            float4 w1 = *(const float4*)&W1[(size_t)(k + kk) * FHID + c0 + 4];
            float av0 = kk == 0 ? a0.x : kk == 1 ? a0.y : kk == 2 ? a0.z : a0.w;
            float av1 = kk == 0 ? a1.x : kk == 1 ? a1.y : kk == 2 ? a1.z : a1.w;
            FMA8(0, av0, w0, w1)
            FMA8(1, av1, w0, w1)
        }
    }
    {
        float4 bA = *(const float4*)&b1[c0];
        float4 bB = *(const float4*)&b1[c0 + 4];
        #pragma unroll
        for (int j = 0; j < 2; ++j) {
            float4 o0 = make_float4(fmaxf(acc[j][0] + bA.x, 0.f), fmaxf(acc[j][1] + bA.y, 0.f),
                                    fmaxf(acc[j][2] + bA.z, 0.f), fmaxf(acc[j][3] + bA.w, 0.f));
            float4 o1 = make_float4(fmaxf(acc[j][4] + bB.x, 0.f), fmaxf(acc[j][5] + bB.y, 0.f),
                                    fmaxf(acc[j][6] + bB.z, 0.f), fmaxf(acc[j][7] + bB.w, 0.f));
            *(float4*)&ldsC[(r0 + j) * CLDS + c0] = o0;
            *(float4*)&ldsC[(r0 + j) * CLDS + c0 + 4] = o1;
        }
    }
    __syncthreads();

    // phase 2: G(16x64) = C @ W2. thread = 4 cols x 1 row
    int c = (tid & 15) * 4, r = tid >> 4;
    float g0 = 0.f, g1 = 0.f, g2 = 0.f, g3 = 0.f;
    for (int k = 0; k < FHID; k += 4) {
        float4 cv = *(const float4*)&ldsC[r * CLDS + k];
        #pragma unroll
        for (int kk = 0; kk < 4; ++kk) {
            float4 wv = *(const float4*)&W2[(size_t)(k + kk) * FOUT + c];
            float av = kk == 0 ? cv.x : kk == 1 ? cv.y : kk == 2 ? cv.z : cv.w;
            g0 += av * wv.x; g1 += av * wv.y; g2 += av * wv.z; g3 += av * wv.w;
        }
    }
    *(float4*)&G[(size_t)(row0 + r) * FOUT + c] = make_float4(g0, g1, g2, g3);
}

// ---------- layer-2 aggregate + bias + softmax: 16-lane group x float4 per node ----------
__global__ __launch_bounds__(256) void k_agg2sm(
    const float* __restrict__ G, const int2* __restrict__ ep,
    const float* __restrict__ dinv, const int* __restrict__ off,
    const float* __restrict__ b2, float* __restrict__ out) {
    int q = threadIdx.x >> 4, l = threadIdx.x & 15;
    int n = (blockIdx.x << 4) + q;
    const float* gc = G + (l << 2);
    float ax = 0.f, ay = 0.f, az = 0.f, aw = 0.f;
    int p = off[n], p1 = off[n + 1];
    for (; p + 4 <= p1; p += 4) {
        int2 e0 = ep[p], e1 = ep[p + 1], e2 = ep[p + 2], e3 = ep[p + 3];
        float4 v0 = *(const float4*)(gc + ((size_t)e0.x << 6));
        float4 v1 = *(const float4*)(gc + ((size_t)e1.x << 6));
        float4 v2 = *(const float4*)(gc + ((size_t)e2.x << 6));
        float4 v3 = *(const float4*)(gc + ((size_t)e3.x << 6));
        float c0 = __int_as_float(e0.y), c1 = __int_as_float(e1.y);
        float c2 = __int_as_float(e2.y), c3 = __int_as_float(e3.y);
        ax += c0 * v0.x + c1 * v1.x + c2 * v2.x + c3 * v3.x;
        ay += c0 * v0.y + c1 * v1.y + c2 * v2.y + c3 * v3.y;
        az += c0 * v0.z + c1 * v1.z + c2 * v2.z + c3 * v3.z;
        aw += c0 * v0.w + c1 * v1.w + c2 * v2.w + c3 * v3.w;
    }
    for (; p < p1; ++p) {
        int2 e = ep[p];
        float4 v = *(const float4*)(gc + ((size_t)e.x << 6));
        float c = __int_as_float(e.y);
        ax += c * v.x; ay += c * v.y; az += c * v.z; aw += c * v.w;
    }
    float dn = dinv[n];
    float s2 = dn * dn;
    float4 gv = *(const float4*)(gc + ((size_t)n << 6));
    float4 bv = *(const float4*)&b2[l << 2];
    ax += s2 * gv.x + bv.x; ay += s2 * gv.y + bv.y;
    az += s2 * gv.z + bv.z; aw += s2 * gv.w + bv.w;

    float m = fmaxf(fmaxf(ax, ay), fmaxf(az, aw));
    #pragma unroll
    for (int d = 8; d; d >>= 1) m = fmaxf(m, __shfl_xor(m, d, 16));
    float ex = __expf(ax - m), ey = __expf(ay - m), ez = __expf(az - m), ew_ = __expf(aw - m);
    float s = ex + ey + ez + ew_;
    #pragma unroll
    for (int d = 8; d; d >>= 1) s += __shfl_xor(s, d, 16);
    float inv = 1.0f / s;
    *(float4*)&out[((size_t)n << 6) + (l << 2)] =
        make_float4(ex * inv, ey * inv, ez * inv, ew_ * inv);
}

extern "C" void kernel_launch(void* const* d_in, const int* in_sizes, int n_in,
                              void* d_out, int out_size, void* d_ws, size_t ws_size,
                              hipStream_t stream) {
    const float* x  = (const float*)d_in[0];
    const int*   ei = (const int*)d_in[1];     // [2, NE]
    const float* ew = (const float*)d_in[2];
    // d_in[3..6] = W_gat, att_src, att_dst, b_gat — DEAD in the reference.
    const float* W1 = (const float*)d_in[7];
    const float* b1 = (const float*)d_in[8];
    const float* W2 = (const float*)d_in[9];
    const float* b2 = (const float*)d_in[10];

    const int* srcv = ei;
    const int* dstv = ei + NE;

    char* ws = (char*)d_ws;
    size_t o = 0;
    auto alloc = [&](size_t bytes) {
        void* p = ws + o;
        o = (o + bytes + 255) & ~(size_t)255;
        return p;
    };
    float* deg  = (float*)alloc(NN * sizeof(float));
    float* dinv = (float*)alloc(NN * sizeof(float));
    int*   cnt  = (int*)alloc(NN * sizeof(int));
    int*   off  = (int*)alloc((NN + 1) * sizeof(int));
    int*   bsum = (int*)alloc(32 * sizeof(int));
    int2*  ep   = (int2*)alloc((size_t)NE * sizeof(int2));
    float* A    = (float*)alloc((size_t)NN * FIN * sizeof(float));
    float* G    = (float*)alloc((size_t)NN * FOUT * sizeof(float));

    k_init   <<<(NN + 255) / 256, 256, 0, stream>>>(deg, cnt);
    k_deg    <<<(NE + 255) / 256, 256, 0, stream>>>(dstv, ew, deg, cnt);
    k_scan1  <<<20, 1024, 0, stream>>>(cnt, deg, dinv, off, bsum);
    k_scan2  <<<1, 64, 0, stream>>>(bsum);
    k_scan3  <<<20, 1024, 0, stream>>>(off, bsum, cnt);
    k_scatter<<<(NE + 255) / 256, 256, 0, stream>>>(srcv, dstv, ew, dinv, off, cnt, ep);
    k_aggx   <<<NN / 8, 256, 0, stream>>>(x, ep, dinv, off, A);
    k_mlp    <<<NN / 16, 256, 0, stream>>>(A, W1, b1, W2, G);
    k_agg2sm <<<NN / 16, 256, 0, stream>>>(G, ep, dinv, off, b2, (float*)d_out);
}

// Round 4
// 146.530 us; speedup vs baseline: 1.2179x; 1.2179x over previous
//
#include <hip/hip_runtime.h>
#include <math.h>

#define NN   20000
#define NE   320000
#define FIN  128
#define FHID 256
#define FOUT 64
#define CLDS 264   // padded phase-2 LDS row stride

// ---------- CSR build ----------
__global__ void k_init(float* deg, int* cnt) {
    int i = blockIdx.x * blockDim.x + threadIdx.x;
    if (i < NN) { deg[i] = 1.0f; cnt[i] = 0; }   // self-loop weight 1.0 pre-added
}

__global__ void k_deg(const int* __restrict__ dst, const float* __restrict__ ew,
                      float* __restrict__ deg, int* __restrict__ cnt) {
    int e = blockIdx.x * blockDim.x + threadIdx.x;
    if (e < NE) {
        int d = dst[e];
        atomicAdd(&deg[d], ew[e]);
        atomicAdd(&cnt[d], 1);
    }
}

// multi-block scan, stage 1: per-block inclusive scan of cnt; also computes dinv
__global__ __launch_bounds__(1024) void k_scan1(
    const int* __restrict__ cnt, const float* __restrict__ deg,
    float* __restrict__ dinv, int* __restrict__ off, int* __restrict__ bsum) {
    __shared__ int wsum[16];
    int tid = threadIdx.x, lane = tid & 63, w = tid >> 6;
    int i = blockIdx.x * 1024 + tid;
    int v = (i < NN) ? cnt[i] : 0;
    if (i < NN) {
        float dg = deg[i];
        dinv[i] = dg > 0.0f ? rsqrtf(dg) : 0.0f;
    }
    int sc = v;
    #pragma unroll
    for (int d = 1; d < 64; d <<= 1) {
        int t = __shfl_up(sc, d, 64);
        if (lane >= d) sc += t;
    }
    if (lane == 63) wsum[w] = sc;
    __syncthreads();
    if (w == 0) {
        int ws_ = (lane < 16) ? wsum[lane] : 0;
        #pragma unroll
        for (int d = 1; d < 16; d <<= 1) {
            int t = __shfl_up(ws_, d, 64);
            if (lane >= d) ws_ += t;
        }
        if (lane < 16) wsum[lane] = ws_;
    }
    __syncthreads();
    int inc = sc + (w ? wsum[w - 1] : 0);
    if (i < NN) off[i + 1] = inc;
    if (tid == 1023) bsum[blockIdx.x] = inc;
}

// stage 2: exclusive scan of the 20 block sums (single wave)
__global__ void k_scan2(int* bsum) {
    int l = threadIdx.x;
    int v = (l < 20) ? bsum[l] : 0;
    int sc = v;
    #pragma unroll
    for (int d = 1; d < 32; d <<= 1) {
        int t = __shfl_up(sc, d, 64);
        if (l >= d) sc += t;
    }
    if (l < 20) bsum[l] = sc - v;
}

// stage 3: add block prefix; zero cnt for scatter
__global__ __launch_bounds__(1024) void k_scan3(int* __restrict__ off,
                                                const int* __restrict__ bsum,
                                                int* __restrict__ cnt) {
    int i = blockIdx.x * 1024 + threadIdx.x;
    if (i < NN) { off[i + 1] += bsum[blockIdx.x]; cnt[i] = 0; }
    if (i == 0) off[0] = 0;
}

// scatter with fully-precomputed coefficient: coef = ew * dinv[s] * dinv[d]
__global__ void k_scatter(const int* __restrict__ src, const int* __restrict__ dst,
                          const float* __restrict__ ew, const float* __restrict__ dinv,
                          const int* __restrict__ off, int* __restrict__ cnt,
                          int2* __restrict__ ep) {
    int e = blockIdx.x * blockDim.x + threadIdx.x;
    if (e < NE) {
        int d = dst[e], s = src[e];
        float c = ew[e] * dinv[s] * dinv[d];
        int p = off[d] + atomicAdd(&cnt[d], 1);
        ep[p] = make_int2(s, __float_as_int(c));
    }
}

// ---------- layer-1 aggregate: A = S @ X. half-wave (32 lanes x float4) per node ----------
__global__ __launch_bounds__(256) void k_aggx(
    const float* __restrict__ x, const int2* __restrict__ ep,
    const float* __restrict__ dinv, const int* __restrict__ off,
    float* __restrict__ A) {
    int half = threadIdx.x >> 5, l = threadIdx.x & 31;
    int n = (blockIdx.x << 3) + half;
    const float* xc = x + (l << 2);
    float ax = 0.f, ay = 0.f, az = 0.f, aw = 0.f;
    int p = off[n], p1 = off[n + 1];
    for (; p + 4 <= p1; p += 4) {
        int2 e0 = ep[p], e1 = ep[p + 1], e2 = ep[p + 2], e3 = ep[p + 3];
        float4 v0 = *(const float4*)(xc + ((size_t)e0.x << 7));
        float4 v1 = *(const float4*)(xc + ((size_t)e1.x << 7));
        float4 v2 = *(const float4*)(xc + ((size_t)e2.x << 7));
        float4 v3 = *(const float4*)(xc + ((size_t)e3.x << 7));
        float c0 = __int_as_float(e0.y), c1 = __int_as_float(e1.y);
        float c2 = __int_as_float(e2.y), c3 = __int_as_float(e3.y);
        ax += c0 * v0.x + c1 * v1.x + c2 * v2.x + c3 * v3.x;
        ay += c0 * v0.y + c1 * v1.y + c2 * v2.y + c3 * v3.y;
        az += c0 * v0.z + c1 * v1.z + c2 * v2.z + c3 * v3.z;
        aw += c0 * v0.w + c1 * v1.w + c2 * v2.w + c3 * v3.w;
    }
    for (; p < p1; ++p) {
        int2 e = ep[p];
        float4 v = *(const float4*)(xc + ((size_t)e.x << 7));
        float c = __int_as_float(e.y);
        ax += c * v.x; ay += c * v.y; az += c * v.z; aw += c * v.w;
    }
    float dn = dinv[n];
    float s2 = dn * dn;
    float4 xv = *(const float4*)(xc + ((size_t)n << 7));
    ax += s2 * xv.x; ay += s2 * xv.y; az += s2 * xv.z; aw += s2 * xv.w;
    *(float4*)(A + ((size_t)n << 7) + (l << 2)) = make_float4(ax, ay, az, aw);
}

// ---------- fused MLP: G = relu(A@W1+b1)@W2, 16 rows/block ----------
// Phase 1: thread = 4 rows x 4 cols; 64 lanes cover all 256 cols (full-width
// dwordx4 W loads, no duplication); ldsA reads are wave-uniform broadcasts.
// Explicit W prefetch (next k-group loaded before current FMAs).
__global__ __launch_bounds__(256, 4) void k_mlp(
    const float* __restrict__ A, const float* __restrict__ W1,
    const float* __restrict__ b1, const float* __restrict__ W2,
    float* __restrict__ G) {
    __shared__ float ldsA[16 * FIN];     // 8 KB
    __shared__ float ldsC[16 * CLDS];    // 16.5 KB
    int tid = threadIdx.x;
    int row0 = blockIdx.x * 16;

    // stage A tile (16 x 128) coalesced
    {
        const float4* Af = (const float4*)(A + (size_t)row0 * FIN);
        float4* Lf = (float4*)ldsA;
        Lf[tid] = Af[tid];
        Lf[tid + 256] = Af[tid + 256];
    }
    __syncthreads();

    // ----- phase 1: C(16x256) = relu(As @ W1 + b1) -----
    {
        int c0 = (tid & 63) << 2;        // 64 colgroups x 4 cols = 256 cols
        int r0 = (tid >> 6) << 2;        // 4 rowgroups x 4 rows  (uniform per wave)
        float acc[4][4] = {};
        float4 w0 = *(const float4*)&W1[(size_t)0 * FHID + c0];
        float4 w1 = *(const float4*)&W1[(size_t)1 * FHID + c0];
        float4 w2 = *(const float4*)&W1[(size_t)2 * FHID + c0];
        float4 w3 = *(const float4*)&W1[(size_t)3 * FHID + c0];
        for (int k = 0; k < FIN; k += 4) {
            float4 a0 = *(const float4*)&ldsA[(r0 + 0) * FIN + k];
            float4 a1 = *(const float4*)&ldsA[(r0 + 1) * FIN + k];
            float4 a2 = *(const float4*)&ldsA[(r0 + 2) * FIN + k];
            float4 a3 = *(const float4*)&ldsA[(r0 + 3) * FIN + k];
            float4 n0, n1, n2, n3;
            if (k + 4 < FIN) {
                n0 = *(const float4*)&W1[(size_t)(k + 4) * FHID + c0];
                n1 = *(const float4*)&W1[(size_t)(k + 5) * FHID + c0];
                n2 = *(const float4*)&W1[(size_t)(k + 6) * FHID + c0];
                n3 = *(const float4*)&W1[(size_t)(k + 7) * FHID + c0];
            }
            #define P1KK(WV, SEL)                                             \
                acc[0][0] += a0.SEL * WV.x; acc[0][1] += a0.SEL * WV.y;       \
                acc[0][2] += a0.SEL * WV.z; acc[0][3] += a0.SEL * WV.w;       \
                acc[1][0] += a1.SEL * WV.x; acc[1][1] += a1.SEL * WV.y;       \
                acc[1][2] += a1.SEL * WV.z; acc[1][3] += a1.SEL * WV.w;       \
                acc[2][0] += a2.SEL * WV.x; acc[2][1] += a2.SEL * WV.y;       \
                acc[2][2] += a2.SEL * WV.z; acc[2][3] += a2.SEL * WV.w;       \
                acc[3][0] += a3.SEL * WV.x; acc[3][1] += a3.SEL * WV.y;       \
                acc[3][2] += a3.SEL * WV.z; acc[3][3] += a3.SEL * WV.w;
            P1KK(w0, x) P1KK(w1, y) P1KK(w2, z) P1KK(w3, w)
            #undef P1KK
            w0 = n0; w1 = n1; w2 = n2; w3 = n3;
        }
        float4 bv = *(const float4*)&b1[c0];
        #pragma unroll
        for (int j = 0; j < 4; ++j) {
            float4 o = make_float4(fmaxf(acc[j][0] + bv.x, 0.f),
                                   fmaxf(acc[j][1] + bv.y, 0.f),
                                   fmaxf(acc[j][2] + bv.z, 0.f),
                                   fmaxf(acc[j][3] + bv.w, 0.f));
            *(float4*)&ldsC[(r0 + j) * CLDS + c0] = o;
        }
    }
    __syncthreads();

    // ----- phase 2: G(16x64) = C @ W2 -----
    {
        int c = tid & 63;                // 64 lanes = 64 distinct cols
        int r0 = (tid >> 6) << 2;        // 4 rows/thread (uniform per wave)
        float g0 = 0.f, g1 = 0.f, g2 = 0.f, g3 = 0.f;
        float u0 = W2[(size_t)0 * FOUT + c];
        float u1 = W2[(size_t)1 * FOUT + c];
        float u2 = W2[(size_t)2 * FOUT + c];
        float u3 = W2[(size_t)3 * FOUT + c];
        for (int k = 0; k < FHID; k += 4) {
            float4 v0 = *(const float4*)&ldsC[(r0 + 0) * CLDS + k];
            float4 v1 = *(const float4*)&ldsC[(r0 + 1) * CLDS + k];
            float4 v2 = *(const float4*)&ldsC[(r0 + 2) * CLDS + k];
            float4 v3 = *(const float4*)&ldsC[(r0 + 3) * CLDS + k];
            float m0, m1, m2, m3;
            if (k + 4 < FHID) {
                m0 = W2[(size_t)(k + 4) * FOUT + c];
                m1 = W2[(size_t)(k + 5) * FOUT + c];
                m2 = W2[(size_t)(k + 6) * FOUT + c];
                m3 = W2[(size_t)(k + 7) * FOUT + c];
            }
            g0 += v0.x * u0 + v0.y * u1 + v0.z * u2 + v0.w * u3;
            g1 += v1.x * u0 + v1.y * u1 + v1.z * u2 + v1.w * u3;
            g2 += v2.x * u0 + v2.y * u1 + v2.z * u2 + v2.w * u3;
            g3 += v3.x * u0 + v3.y * u1 + v3.z * u2 + v3.w * u3;
            u0 = m0; u1 = m1; u2 = m2; u3 = m3;
        }
        G[(size_t)(row0 + r0 + 0) * FOUT + c] = g0;
        G[(size_t)(row0 + r0 + 1) * FOUT + c] = g1;
        G[(size_t)(row0 + r0 + 2) * FOUT + c] = g2;
        G[(size_t)(row0 + r0 + 3) * FOUT + c] = g3;
    }
}

// ---------- layer-2 aggregate + bias + softmax: 16-lane group x float4 per node ----------
__global__ __launch_bounds__(256) void k_agg2sm(
    const float* __restrict__ G, const int2* __restrict__ ep,
    const float* __restrict__ dinv, const int* __restrict__ off,
    const float* __restrict__ b2, float* __restrict__ out) {
    int q = threadIdx.x >> 4, l = threadIdx.x & 15;
    int n = (blockIdx.x << 4) + q;
    const float* gc = G + (l << 2);
    float ax = 0.f, ay = 0.f, az = 0.f, aw = 0.f;
    int p = off[n], p1 = off[n + 1];
    for (; p + 4 <= p1; p += 4) {
        int2 e0 = ep[p], e1 = ep[p + 1], e2 = ep[p + 2], e3 = ep[p + 3];
        float4 v0 = *(const float4*)(gc + ((size_t)e0.x << 6));
        float4 v1 = *(const float4*)(gc + ((size_t)e1.x << 6));
        float4 v2 = *(const float4*)(gc + ((size_t)e2.x << 6));
        float4 v3 = *(const float4*)(gc + ((size_t)e3.x << 6));
        float c0 = __int_as_float(e0.y), c1 = __int_as_float(e1.y);
        float c2 = __int_as_float(e2.y), c3 = __int_as_float(e3.y);
        ax += c0 * v0.x + c1 * v1.x + c2 * v2.x + c3 * v3.x;
        ay += c0 * v0.y + c1 * v1.y + c2 * v2.y + c3 * v3.y;
        az += c0 * v0.z + c1 * v1.z + c2 * v2.z + c3 * v3.z;
        aw += c0 * v0.w + c1 * v1.w + c2 * v2.w + c3 * v3.w;
    }
    for (; p < p1; ++p) {
        int2 e = ep[p];
        float4 v = *(const float4*)(gc + ((size_t)e.x << 6));
        float c = __int_as_float(e.y);
        ax += c * v.x; ay += c * v.y; az += c * v.z; aw += c * v.w;
    }
    float dn = dinv[n];
    float s2 = dn * dn;
    float4 gv = *(const float4*)(gc + ((size_t)n << 6));
    float4 bv = *(const float4*)&b2[l << 2];
    ax += s2 * gv.x + bv.x; ay += s2 * gv.y + bv.y;
    az += s2 * gv.z + bv.z; aw += s2 * gv.w + bv.w;

    float m = fmaxf(fmaxf(ax, ay), fmaxf(az, aw));
    #pragma unroll
    for (int d = 8; d; d >>= 1) m = fmaxf(m, __shfl_xor(m, d, 16));
    float ex = __expf(ax - m), ey = __expf(ay - m), ez = __expf(az - m), ew_ = __expf(aw - m);
    float s = ex + ey + ez + ew_;
    #pragma unroll
    for (int d = 8; d; d >>= 1) s += __shfl_xor(s, d, 16);
    float inv = 1.0f / s;
    *(float4*)&out[((size_t)n << 6) + (l << 2)] =
        make_float4(ex * inv, ey * inv, ez * inv, ew_ * inv);
}

extern "C" void kernel_launch(void* const* d_in, const int* in_sizes, int n_in,
                              void* d_out, int out_size, void* d_ws, size_t ws_size,
                              hipStream_t stream) {
    const float* x  = (const float*)d_in[0];
    const int*   ei = (const int*)d_in[1];     // [2, NE]
    const float* ew = (const float*)d_in[2];
    // d_in[3..6] = W_gat, att_src, att_dst, b_gat — DEAD in the reference.
    const float* W1 = (const float*)d_in[7];
    const float* b1 = (const float*)d_in[8];
    const float* W2 = (const float*)d_in[9];
    const float* b2 = (const float*)d_in[10];

    const int* srcv = ei;
    const int* dstv = ei + NE;

    char* ws = (char*)d_ws;
    size_t o = 0;
    auto alloc = [&](size_t bytes) {
        void* p = ws + o;
        o = (o + bytes + 255) & ~(size_t)255;
        return p;
    };
    float* deg  = (float*)alloc(NN * sizeof(float));
    float* dinv = (float*)alloc(NN * sizeof(float));
    int*   cnt  = (int*)alloc(NN * sizeof(int));
    int*   off  = (int*)alloc((NN + 1) * sizeof(int));
    int*   bsum = (int*)alloc(32 * sizeof(int));
    int2*  ep   = (int2*)alloc((size_t)NE * sizeof(int2));
    float* A    = (float*)alloc((size_t)NN * FIN * sizeof(float));
    float* G    = (float*)alloc((size_t)NN * FOUT * sizeof(float));

    k_init   <<<(NN + 255) / 256, 256, 0, stream>>>(deg, cnt);
    k_deg    <<<(NE + 255) / 256, 256, 0, stream>>>(dstv, ew, deg, cnt);
    k_scan1  <<<20, 1024, 0, stream>>>(cnt, deg, dinv, off, bsum);
    k_scan2  <<<1, 64, 0, stream>>>(bsum);
    k_scan3  <<<20, 1024, 0, stream>>>(off, bsum, cnt);
    k_scatter<<<(NE + 255) / 256, 256, 0, stream>>>(srcv, dstv, ew, dinv, off, cnt, ep);
    k_aggx   <<<NN / 8, 256, 0, stream>>>(x, ep, dinv, off, A);
    k_mlp    <<<NN / 16, 256, 0, stream>>>(A, W1, b1, W2, G);
    k_agg2sm <<<NN / 16, 256, 0, stream>>>(G, ep, dinv, off, b2, (float*)d_out);
}

// Round 5
// 139.560 us; speedup vs baseline: 1.2787x; 1.0499x over previous
//
#include <hip/hip_runtime.h>
#include <math.h>

#define NN   20000
#define NE   320000
#define FIN  128
#define FHID 256
#define FOUT 64
#define CLDS 264   // padded phase-2 LDS row stride

// ---------- CSR build ----------
__global__ void k_init(float* deg, int* cnt) {
    int i = blockIdx.x * blockDim.x + threadIdx.x;
    if (i < NN) { deg[i] = 1.0f; cnt[i] = 0; }   // self-loop weight 1.0 pre-added
}

__global__ void k_deg(const int* __restrict__ dst, const float* __restrict__ ew,
                      float* __restrict__ deg, int* __restrict__ cnt) {
    int e = blockIdx.x * blockDim.x + threadIdx.x;
    if (e < NE) {
        int d = dst[e];
        atomicAdd(&deg[d], ew[e]);
        atomicAdd(&cnt[d], 1);
    }
}

// multi-block scan, stage 1: per-block inclusive scan of cnt; also computes dinv
__global__ __launch_bounds__(1024) void k_scan1(
    const int* __restrict__ cnt, const float* __restrict__ deg,
    float* __restrict__ dinv, int* __restrict__ off, int* __restrict__ bsum) {
    __shared__ int wsum[16];
    int tid = threadIdx.x, lane = tid & 63, w = tid >> 6;
    int i = blockIdx.x * 1024 + tid;
    int v = (i < NN) ? cnt[i] : 0;
    if (i < NN) {
        float dg = deg[i];
        dinv[i] = dg > 0.0f ? rsqrtf(dg) : 0.0f;
    }
    int sc = v;
    #pragma unroll
    for (int d = 1; d < 64; d <<= 1) {
        int t = __shfl_up(sc, d, 64);
        if (lane >= d) sc += t;
    }
    if (lane == 63) wsum[w] = sc;
    __syncthreads();
    if (w == 0) {
        int ws_ = (lane < 16) ? wsum[lane] : 0;
        #pragma unroll
        for (int d = 1; d < 16; d <<= 1) {
            int t = __shfl_up(ws_, d, 64);
            if (lane >= d) ws_ += t;
        }
        if (lane < 16) wsum[lane] = ws_;
    }
    __syncthreads();
    int inc = sc + (w ? wsum[w - 1] : 0);
    if (i < NN) off[i + 1] = inc;
    if (tid == 1023) bsum[blockIdx.x] = inc;
}

// stage 2: exclusive scan of the 20 block sums (single wave)
__global__ void k_scan2(int* bsum) {
    int l = threadIdx.x;
    int v = (l < 20) ? bsum[l] : 0;
    int sc = v;
    #pragma unroll
    for (int d = 1; d < 32; d <<= 1) {
        int t = __shfl_up(sc, d, 64);
        if (l >= d) sc += t;
    }
    if (l < 20) bsum[l] = sc - v;
}

// stage 3: add block prefix; zero cnt for scatter
__global__ __launch_bounds__(1024) void k_scan3(int* __restrict__ off,
                                                const int* __restrict__ bsum,
                                                int* __restrict__ cnt) {
    int i = blockIdx.x * 1024 + threadIdx.x;
    if (i < NN) { off[i + 1] += bsum[blockIdx.x]; cnt[i] = 0; }
    if (i == 0) off[0] = 0;
}

// scatter with fully-precomputed coefficient: coef = ew * dinv[s] * dinv[d]
__global__ void k_scatter(const int* __restrict__ src, const int* __restrict__ dst,
                          const float* __restrict__ ew, const float* __restrict__ dinv,
                          const int* __restrict__ off, int* __restrict__ cnt,
                          int2* __restrict__ ep) {
    int e = blockIdx.x * blockDim.x + threadIdx.x;
    if (e < NE) {
        int d = dst[e], s = src[e];
        float c = ew[e] * dinv[s] * dinv[d];
        int p = off[d] + atomicAdd(&cnt[d], 1);
        ep[p] = make_int2(s, __float_as_int(c));
    }
}

// ---------- layer-1 aggregate: A = S @ X. half-wave (32 lanes x float4) per node ----------
__global__ __launch_bounds__(256) void k_aggx(
    const float* __restrict__ x, const int2* __restrict__ ep,
    const float* __restrict__ dinv, const int* __restrict__ off,
    float* __restrict__ A) {
    int half = threadIdx.x >> 5, l = threadIdx.x & 31;
    int n = (blockIdx.x << 3) + half;
    const float* xc = x + (l << 2);
    float ax = 0.f, ay = 0.f, az = 0.f, aw = 0.f;
    int p = off[n], p1 = off[n + 1];
    for (; p + 4 <= p1; p += 4) {
        int2 e0 = ep[p], e1 = ep[p + 1], e2 = ep[p + 2], e3 = ep[p + 3];
        float4 v0 = *(const float4*)(xc + ((size_t)e0.x << 7));
        float4 v1 = *(const float4*)(xc + ((size_t)e1.x << 7));
        float4 v2 = *(const float4*)(xc + ((size_t)e2.x << 7));
        float4 v3 = *(const float4*)(xc + ((size_t)e3.x << 7));
        float c0 = __int_as_float(e0.y), c1 = __int_as_float(e1.y);
        float c2 = __int_as_float(e2.y), c3 = __int_as_float(e3.y);
        ax += c0 * v0.x + c1 * v1.x + c2 * v2.x + c3 * v3.x;
        ay += c0 * v0.y + c1 * v1.y + c2 * v2.y + c3 * v3.y;
        az += c0 * v0.z + c1 * v1.z + c2 * v2.z + c3 * v3.z;
        aw += c0 * v0.w + c1 * v1.w + c2 * v2.w + c3 * v3.w;
    }
    for (; p < p1; ++p) {
        int2 e = ep[p];
        float4 v = *(const float4*)(xc + ((size_t)e.x << 7));
        float c = __int_as_float(e.y);
        ax += c * v.x; ay += c * v.y; az += c * v.z; aw += c * v.w;
    }
    float dn = dinv[n];
    float s2 = dn * dn;
    float4 xv = *(const float4*)(xc + ((size_t)n << 7));
    ax += s2 * xv.x; ay += s2 * xv.y; az += s2 * xv.z; aw += s2 * xv.w;
    *(float4*)(A + ((size_t)n << 7) + (l << 2)) = make_float4(ax, ay, az, aw);
}

// ---------- fused MLP: G = relu(A@W1+b1)@W2, 16 rows/block ----------
// Phase 1: thread = 4 rows x 4 cols; 64 lanes cover all 256 cols. Fully
// unrolled k-loops (all offsets compile-time) so the scheduler hoists W
// loads across iterations — register-level software pipelining.
__global__ __launch_bounds__(256, 4) void k_mlp(
    const float* __restrict__ A, const float* __restrict__ W1,
    const float* __restrict__ b1, const float* __restrict__ W2,
    float* __restrict__ G) {
    __shared__ float ldsA[16 * FIN];     // 8 KB
    __shared__ float ldsC[16 * CLDS];    // 16.5 KB
    int tid = threadIdx.x;
    int row0 = blockIdx.x * 16;

    // stage A tile (16 x 128) coalesced
    {
        const float4* Af = (const float4*)(A + (size_t)row0 * FIN);
        float4* Lf = (float4*)ldsA;
        Lf[tid] = Af[tid];
        Lf[tid + 256] = Af[tid + 256];
    }
    __syncthreads();

    // ----- phase 1: C(16x256) = relu(As @ W1 + b1) -----
    {
        int c0 = (tid & 63) << 2;        // 64 colgroups x 4 cols = 256 cols
        int r0 = (tid >> 6) << 2;        // 4 rows/thread (uniform per wave)
        const float* Wp = W1 + c0;
        const float* Ap = ldsA + r0 * FIN;
        float acc[4][4] = {};
        #pragma unroll
        for (int k = 0; k < FIN; k += 4) {
            float4 w0 = *(const float4*)(Wp + (size_t)(k + 0) * FHID);
            float4 w1 = *(const float4*)(Wp + (size_t)(k + 1) * FHID);
            float4 w2 = *(const float4*)(Wp + (size_t)(k + 2) * FHID);
            float4 w3 = *(const float4*)(Wp + (size_t)(k + 3) * FHID);
            float4 a0 = *(const float4*)(Ap + 0 * FIN + k);
            float4 a1 = *(const float4*)(Ap + 1 * FIN + k);
            float4 a2 = *(const float4*)(Ap + 2 * FIN + k);
            float4 a3 = *(const float4*)(Ap + 3 * FIN + k);
            #define P1KK(WV, SEL)                                             \
                acc[0][0] += a0.SEL * WV.x; acc[0][1] += a0.SEL * WV.y;       \
                acc[0][2] += a0.SEL * WV.z; acc[0][3] += a0.SEL * WV.w;       \
                acc[1][0] += a1.SEL * WV.x; acc[1][1] += a1.SEL * WV.y;       \
                acc[1][2] += a1.SEL * WV.z; acc[1][3] += a1.SEL * WV.w;       \
                acc[2][0] += a2.SEL * WV.x; acc[2][1] += a2.SEL * WV.y;       \
                acc[2][2] += a2.SEL * WV.z; acc[2][3] += a2.SEL * WV.w;       \
                acc[3][0] += a3.SEL * WV.x; acc[3][1] += a3.SEL * WV.y;       \
                acc[3][2] += a3.SEL * WV.z; acc[3][3] += a3.SEL * WV.w;
            P1KK(w0, x) P1KK(w1, y) P1KK(w2, z) P1KK(w3, w)
            #undef P1KK
        }
        float4 bv = *(const float4*)&b1[c0];
        #pragma unroll
        for (int j = 0; j < 4; ++j) {
            float4 o = make_float4(fmaxf(acc[j][0] + bv.x, 0.f),
                                   fmaxf(acc[j][1] + bv.y, 0.f),
                                   fmaxf(acc[j][2] + bv.z, 0.f),
                                   fmaxf(acc[j][3] + bv.w, 0.f));
            *(float4*)&ldsC[(r0 + j) * CLDS + c0] = o;
        }
    }
    __syncthreads();

    // ----- phase 2: G(16x64) = C @ W2 -----
    {
        int c = tid & 63;                // 64 lanes = 64 distinct cols
        int r0 = (tid >> 6) << 2;        // 4 rows/thread (uniform per wave)
        const float* Up = W2 + c;
        const float* Cp = ldsC + r0 * CLDS;
        float g0 = 0.f, g1 = 0.f, g2 = 0.f, g3 = 0.f;
        #pragma unroll
        for (int k = 0; k < FHID; k += 4) {
            float u0 = Up[(size_t)(k + 0) * FOUT];
            float u1 = Up[(size_t)(k + 1) * FOUT];
            float u2 = Up[(size_t)(k + 2) * FOUT];
            float u3 = Up[(size_t)(k + 3) * FOUT];
            float4 v0 = *(const float4*)(Cp + 0 * CLDS + k);
            float4 v1 = *(const float4*)(Cp + 1 * CLDS + k);
            float4 v2 = *(const float4*)(Cp + 2 * CLDS + k);
            float4 v3 = *(const float4*)(Cp + 3 * CLDS + k);
            g0 += v0.x * u0 + v0.y * u1 + v0.z * u2 + v0.w * u3;
            g1 += v1.x * u0 + v1.y * u1 + v1.z * u2 + v1.w * u3;
            g2 += v2.x * u0 + v2.y * u1 + v2.z * u2 + v2.w * u3;
            g3 += v3.x * u0 + v3.y * u1 + v3.z * u2 + v3.w * u3;
        }
        G[(size_t)(row0 + r0 + 0) * FOUT + c] = g0;
        G[(size_t)(row0 + r0 + 1) * FOUT + c] = g1;
        G[(size_t)(row0 + r0 + 2) * FOUT + c] = g2;
        G[(size_t)(row0 + r0 + 3) * FOUT + c] = g3;
    }
}

// ---------- layer-2 aggregate + bias + softmax: 16-lane group x float4 per node ----------
__global__ __launch_bounds__(256) void k_agg2sm(
    const float* __restrict__ G, const int2* __restrict__ ep,
    const float* __restrict__ dinv, const int* __restrict__ off,
    const float* __restrict__ b2, float* __restrict__ out) {
    int q = threadIdx.x >> 4, l = threadIdx.x & 15;
    int n = (blockIdx.x << 4) + q;
    const float* gc = G + (l << 2);
    float ax = 0.f, ay = 0.f, az = 0.f, aw = 0.f;
    int p = off[n], p1 = off[n + 1];
    for (; p + 4 <= p1; p += 4) {
        int2 e0 = ep[p], e1 = ep[p + 1], e2 = ep[p + 2], e3 = ep[p + 3];
        float4 v0 = *(const float4*)(gc + ((size_t)e0.x << 6));
        float4 v1 = *(const float4*)(gc + ((size_t)e1.x << 6));
        float4 v2 = *(const float4*)(gc + ((size_t)e2.x << 6));
        float4 v3 = *(const float4*)(gc + ((size_t)e3.x << 6));
        float c0 = __int_as_float(e0.y), c1 = __int_as_float(e1.y);
        float c2 = __int_as_float(e2.y), c3 = __int_as_float(e3.y);
        ax += c0 * v0.x + c1 * v1.x + c2 * v2.x + c3 * v3.x;
        ay += c0 * v0.y + c1 * v1.y + c2 * v2.y + c3 * v3.y;
        az += c0 * v0.z + c1 * v1.z + c2 * v2.z + c3 * v3.z;
        aw += c0 * v0.w + c1 * v1.w + c2 * v2.w + c3 * v3.w;
    }
    for (; p < p1; ++p) {
        int2 e = ep[p];
        float4 v = *(const float4*)(gc + ((size_t)e.x << 6));
        float c = __int_as_float(e.y);
        ax += c * v.x; ay += c * v.y; az += c * v.z; aw += c * v.w;
    }
    float dn = dinv[n];
    float s2 = dn * dn;
    float4 gv = *(const float4*)(gc + ((size_t)n << 6));
    float4 bv = *(const float4*)&b2[l << 2];
    ax += s2 * gv.x + bv.x; ay += s2 * gv.y + bv.y;
    az += s2 * gv.z + bv.z; aw += s2 * gv.w + bv.w;

    float m = fmaxf(fmaxf(ax, ay), fmaxf(az, aw));
    #pragma unroll
    for (int d = 8; d; d >>= 1) m = fmaxf(m, __shfl_xor(m, d, 16));
    float ex = __expf(ax - m), ey = __expf(ay - m), ez = __expf(az - m), ew_ = __expf(aw - m);
    float s = ex + ey + ez + ew_;
    #pragma unroll
    for (int d = 8; d; d >>= 1) s += __shfl_xor(s, d, 16);
    float inv = 1.0f / s;
    *(float4*)&out[((size_t)n << 6) + (l << 2)] =
        make_float4(ex * inv, ey * inv, ez * inv, ew_ * inv);
}

extern "C" void kernel_launch(void* const* d_in, const int* in_sizes, int n_in,
                              void* d_out, int out_size, void* d_ws, size_t ws_size,
                              hipStream_t stream) {
    const float* x  = (const float*)d_in[0];
    const int*   ei = (const int*)d_in[1];     // [2, NE]
    const float* ew = (const float*)d_in[2];
    // d_in[3..6] = W_gat, att_src, att_dst, b_gat — DEAD in the reference.
    const float* W1 = (const float*)d_in[7];
    const float* b1 = (const float*)d_in[8];
    const float* W2 = (const float*)d_in[9];
    const float* b2 = (const float*)d_in[10];

    const int* srcv = ei;
    const int* dstv = ei + NE;

    char* ws = (char*)d_ws;
    size_t o = 0;
    auto alloc = [&](size_t bytes) {
        void* p = ws + o;
        o = (o + bytes + 255) & ~(size_t)255;
        return p;
    };
    float* deg  = (float*)alloc(NN * sizeof(float));
    float* dinv = (float*)alloc(NN * sizeof(float));
    int*   cnt  = (int*)alloc(NN * sizeof(int));
    int*   off  = (int*)alloc((NN + 1) * sizeof(int));
    int*   bsum = (int*)alloc(32 * sizeof(int));
    int2*  ep   = (int2*)alloc((size_t)NE * sizeof(int2));
    float* A    = (float*)alloc((size_t)NN * FIN * sizeof(float));
    float* G    = (float*)alloc((size_t)NN * FOUT * sizeof(float));

    k_init   <<<(NN + 255) / 256, 256, 0, stream>>>(deg, cnt);
    k_deg    <<<(NE + 255) / 256, 256, 0, stream>>>(dstv, ew, deg, cnt);
    k_scan1  <<<20, 1024, 0, stream>>>(cnt, deg, dinv, off, bsum);
    k_scan2  <<<1, 64, 0, stream>>>(bsum);
    k_scan3  <<<20, 1024, 0, stream>>>(off, bsum, cnt);
    k_scatter<<<(NE + 255) / 256, 256, 0, stream>>>(srcv, dstv, ew, dinv, off, cnt, ep);
    k_aggx   <<<NN / 8, 256, 0, stream>>>(x, ep, dinv, off, A);
    k_mlp    <<<NN / 16, 256, 0, stream>>>(A, W1, b1, W2, G);
    k_agg2sm <<<NN / 16, 256, 0, stream>>>(G, ep, dinv, off, b2, (float*)d_out);
}

// Round 6
// 122.630 us; speedup vs baseline: 1.4553x; 1.1381x over previous
//
#include <hip/hip_runtime.h>
#include <math.h>

#define NN   20000
#define NE   320000
#define FIN  128
#define FHID 256
#define FOUT 64
#define CLDS 268   // fp32 C-tile LDS row stride (268%32=12 -> benign 2-way patterns)

typedef __attribute__((ext_vector_type(8))) __bf16 bf16x8;
typedef __attribute__((ext_vector_type(4))) float  f32x4;

union FragU { unsigned short us[8]; bf16x8 v; uint4 q; };

static __device__ __forceinline__ unsigned short f2bf(float f) {
    unsigned u = __float_as_uint(f);
    return (unsigned short)((u + 0x7FFFu + ((u >> 16) & 1u)) >> 16);
}

// ---------- CSR build ----------
__global__ void k_init(float* deg, int* cnt) {
    int i = blockIdx.x * blockDim.x + threadIdx.x;
    if (i < NN) { deg[i] = 1.0f; cnt[i] = 0; }   // self-loop weight 1.0 pre-added
}

__global__ void k_deg(const int* __restrict__ dst, const float* __restrict__ ew,
                      float* __restrict__ deg, int* __restrict__ cnt) {
    int e = blockIdx.x * blockDim.x + threadIdx.x;
    if (e < NE) {
        int d = dst[e];
        atomicAdd(&deg[d], ew[e]);
        atomicAdd(&cnt[d], 1);
    }
}

// multi-block scan, stage 1: per-block inclusive scan of cnt; also computes dinv
__global__ __launch_bounds__(1024) void k_scan1(
    const int* __restrict__ cnt, const float* __restrict__ deg,
    float* __restrict__ dinv, int* __restrict__ off, int* __restrict__ bsum) {
    __shared__ int wsum[16];
    int tid = threadIdx.x, lane = tid & 63, w = tid >> 6;
    int i = blockIdx.x * 1024 + tid;
    int v = (i < NN) ? cnt[i] : 0;
    if (i < NN) {
        float dg = deg[i];
        dinv[i] = dg > 0.0f ? rsqrtf(dg) : 0.0f;
    }
    int sc = v;
    #pragma unroll
    for (int d = 1; d < 64; d <<= 1) {
        int t = __shfl_up(sc, d, 64);
        if (lane >= d) sc += t;
    }
    if (lane == 63) wsum[w] = sc;
    __syncthreads();
    if (w == 0) {
        int ws_ = (lane < 16) ? wsum[lane] : 0;
        #pragma unroll
        for (int d = 1; d < 16; d <<= 1) {
            int t = __shfl_up(ws_, d, 64);
            if (lane >= d) ws_ += t;
        }
        if (lane < 16) wsum[lane] = ws_;
    }
    __syncthreads();
    int inc = sc + (w ? wsum[w - 1] : 0);
    if (i < NN) off[i + 1] = inc;
    if (tid == 1023) bsum[blockIdx.x] = inc;
}

// stage 2: exclusive scan of the 20 block sums (single wave)
__global__ void k_scan2(int* bsum) {
    int l = threadIdx.x;
    int v = (l < 20) ? bsum[l] : 0;
    int sc = v;
    #pragma unroll
    for (int d = 1; d < 32; d <<= 1) {
        int t = __shfl_up(sc, d, 64);
        if (l >= d) sc += t;
    }
    if (l < 20) bsum[l] = sc - v;
}

// stage 3: add block prefix; zero cnt for scatter
__global__ __launch_bounds__(1024) void k_scan3(int* __restrict__ off,
                                                const int* __restrict__ bsum,
                                                int* __restrict__ cnt) {
    int i = blockIdx.x * 1024 + threadIdx.x;
    if (i < NN) { off[i + 1] += bsum[blockIdx.x]; cnt[i] = 0; }
    if (i == 0) off[0] = 0;
}

// scatter with fully-precomputed coefficient: coef = ew * dinv[s] * dinv[d]
__global__ void k_scatter(const int* __restrict__ src, const int* __restrict__ dst,
                          const float* __restrict__ ew, const float* __restrict__ dinv,
                          const int* __restrict__ off, int* __restrict__ cnt,
                          int2* __restrict__ ep) {
    int e = blockIdx.x * blockDim.x + threadIdx.x;
    if (e < NE) {
        int d = dst[e], s = src[e];
        float c = ew[e] * dinv[s] * dinv[d];
        int p = off[d] + atomicAdd(&cnt[d], 1);
        ep[p] = make_int2(s, __float_as_int(c));
    }
}

// ---------- pack W ([K][N] fp32, row-major) into MFMA B-fragment tiles, hi/lo bf16 ----------
// pk[((kt*NT + nt)*64 + lane)*8 + j];  B-frag: col = nt*16 + (lane&15), k = kt*32 + (lane>>4)*8 + j
__global__ void k_wpack(const float* __restrict__ W, int K, int N,
                        unsigned short* __restrict__ hi, unsigned short* __restrict__ lo) {
    int t = blockIdx.x * blockDim.x + threadIdx.x;
    int NT = N >> 4, KT = K >> 5;
    if (t >= KT * NT * 64) return;
    int lane = t & 63;
    int tile = t >> 6;
    int nt = tile % NT, kt = tile / NT;
    int col = nt * 16 + (lane & 15);
    int k0 = kt * 32 + (lane >> 4) * 8;
    #pragma unroll
    for (int j = 0; j < 8; ++j) {
        float w = W[(size_t)(k0 + j) * N + col];
        unsigned short h = f2bf(w);
        unsigned short l = f2bf(w - __uint_as_float((unsigned)h << 16));
        hi[(size_t)t * 8 + j] = h;
        lo[(size_t)t * 8 + j] = l;
    }
}

// ---------- layer-1 aggregate: A = S @ X. half-wave (32 lanes x float4) per node ----------
__global__ __launch_bounds__(256) void k_aggx(
    const float* __restrict__ x, const int2* __restrict__ ep,
    const float* __restrict__ dinv, const int* __restrict__ off,
    float* __restrict__ A) {
    int half = threadIdx.x >> 5, l = threadIdx.x & 31;
    int n = (blockIdx.x << 3) + half;
    const float* xc = x + (l << 2);
    float ax = 0.f, ay = 0.f, az = 0.f, aw = 0.f;
    int p = off[n], p1 = off[n + 1];
    for (; p + 4 <= p1; p += 4) {
        int2 e0 = ep[p], e1 = ep[p + 1], e2 = ep[p + 2], e3 = ep[p + 3];
        float4 v0 = *(const float4*)(xc + ((size_t)e0.x << 7));
        float4 v1 = *(const float4*)(xc + ((size_t)e1.x << 7));
        float4 v2 = *(const float4*)(xc + ((size_t)e2.x << 7));
        float4 v3 = *(const float4*)(xc + ((size_t)e3.x << 7));
        float c0 = __int_as_float(e0.y), c1 = __int_as_float(e1.y);
        float c2 = __int_as_float(e2.y), c3 = __int_as_float(e3.y);
        ax += c0 * v0.x + c1 * v1.x + c2 * v2.x + c3 * v3.x;
        ay += c0 * v0.y + c1 * v1.y + c2 * v2.y + c3 * v3.y;
        az += c0 * v0.z + c1 * v1.z + c2 * v2.z + c3 * v3.z;
        aw += c0 * v0.w + c1 * v1.w + c2 * v2.w + c3 * v3.w;
    }
    for (; p < p1; ++p) {
        int2 e = ep[p];
        float4 v = *(const float4*)(xc + ((size_t)e.x << 7));
        float c = __int_as_float(e.y);
        ax += c * v.x; ay += c * v.y; az += c * v.z; aw += c * v.w;
    }
    float dn = dinv[n];
    float s2 = dn * dn;
    float4 xv = *(const float4*)(xc + ((size_t)n << 7));
    ax += s2 * xv.x; ay += s2 * xv.y; az += s2 * xv.z; aw += s2 * xv.w;
    *(float4*)(A + ((size_t)n << 7) + (l << 2)) = make_float4(ax, ay, az, aw);
}

// ---------- fused MLP on matrix cores, split-bf16 (exact to ~2^-17 rel) ----------
// 16 rows/block, 256 thr = 4 waves. Phase 1: wave w -> n-tiles 4w..4w+3 of 16.
// Phase 2: wave w -> n-tile w of 4. 4 MFMA passes: (Ah+Al)x(Wh+Wl).
__global__ __launch_bounds__(256, 4) void k_mlp(
    const float* __restrict__ A,
    const unsigned short* __restrict__ W1h, const unsigned short* __restrict__ W1l,
    const float* __restrict__ b1,
    const unsigned short* __restrict__ W2h, const unsigned short* __restrict__ W2l,
    float* __restrict__ G) {
    __shared__ unsigned short ApkH[4 * 64 * 8];   // 4 KB  [kt][lane][8]
    __shared__ unsigned short ApkL[4 * 64 * 8];   // 4 KB
    __shared__ float ldsC[16 * CLDS];             // 17.2 KB
    int tid = threadIdx.x;
    int lane = tid & 63, w = tid >> 6;
    int row0 = blockIdx.x * 16;
    int colb = lane & 15, kg = lane >> 4;
    int rowb = kg * 4;

    // ---- stage A (16x128) as split-bf16 A-fragments: thread = (kt=w, lane) ----
    {
        const float* ap = A + (size_t)(row0 + colb) * FIN + w * 32 + kg * 8;
        float4 f0 = *(const float4*)ap;
        float4 f1 = *(const float4*)(ap + 4);
        float fs[8] = {f0.x, f0.y, f0.z, f0.w, f1.x, f1.y, f1.z, f1.w};
        FragU h, l;
        #pragma unroll
        for (int j = 0; j < 8; ++j) {
            h.us[j] = f2bf(fs[j]);
            l.us[j] = f2bf(fs[j] - __uint_as_float((unsigned)h.us[j] << 16));
        }
        *(uint4*)&ApkH[tid * 8] = h.q;
        *(uint4*)&ApkL[tid * 8] = l.q;
    }
    __syncthreads();

    // ---- phase 1: C(16x256) = relu(A @ W1 + b1) ----
    {
        f32x4 acc[4];
        #pragma unroll
        for (int f = 0; f < 4; ++f) acc[f] = (f32x4){0.f, 0.f, 0.f, 0.f};
        #pragma unroll
        for (int kt = 0; kt < 4; ++kt) {
            bf16x8 ah = *(const bf16x8*)&ApkH[(kt * 64 + lane) * 8];
            bf16x8 al = *(const bf16x8*)&ApkL[(kt * 64 + lane) * 8];
            #pragma unroll
            for (int f = 0; f < 4; ++f) {
                int nt = w * 4 + f;
                size_t o8 = ((size_t)(kt * 16 + nt) * 64 + lane) * 8;
                bf16x8 bh = *(const bf16x8*)&W1h[o8];
                bf16x8 bl = *(const bf16x8*)&W1l[o8];
                acc[f] = __builtin_amdgcn_mfma_f32_16x16x32_bf16(ah, bh, acc[f], 0, 0, 0);
                acc[f] = __builtin_amdgcn_mfma_f32_16x16x32_bf16(ah, bl, acc[f], 0, 0, 0);
                acc[f] = __builtin_amdgcn_mfma_f32_16x16x32_bf16(al, bh, acc[f], 0, 0, 0);
                acc[f] = __builtin_amdgcn_mfma_f32_16x16x32_bf16(al, bl, acc[f], 0, 0, 0);
            }
        }
        // bias + relu -> fp32 LDS (C/D map: col=lane&15, row=kg*4+r)
        #pragma unroll
        for (int f = 0; f < 4; ++f) {
            int nt = w * 4 + f;
            float bias = b1[nt * 16 + colb];
            #pragma unroll
            for (int r = 0; r < 4; ++r)
                ldsC[(rowb + r) * CLDS + nt * 16 + colb] = fmaxf(acc[f][r] + bias, 0.f);
        }
    }
    __syncthreads();

    // ---- phase 2: G(16x64) = C @ W2 ----
    {
        f32x4 acc2 = (f32x4){0.f, 0.f, 0.f, 0.f};
        #pragma unroll
        for (int kt = 0; kt < 8; ++kt) {
            const float* cp = &ldsC[colb * CLDS + kt * 32 + kg * 8];
            float4 c0 = *(const float4*)cp;
            float4 c1 = *(const float4*)(cp + 4);
            float fs[8] = {c0.x, c0.y, c0.z, c0.w, c1.x, c1.y, c1.z, c1.w};
            FragU h, l;
            #pragma unroll
            for (int j = 0; j < 8; ++j) {
                h.us[j] = f2bf(fs[j]);
                l.us[j] = f2bf(fs[j] - __uint_as_float((unsigned)h.us[j] << 16));
            }
            size_t o8 = ((size_t)(kt * 4 + w) * 64 + lane) * 8;
            bf16x8 bh = *(const bf16x8*)&W2h[o8];
            bf16x8 bl = *(const bf16x8*)&W2l[o8];
            acc2 = __builtin_amdgcn_mfma_f32_16x16x32_bf16(h.v, bh, acc2, 0, 0, 0);
            acc2 = __builtin_amdgcn_mfma_f32_16x16x32_bf16(h.v, bl, acc2, 0, 0, 0);
            acc2 = __builtin_amdgcn_mfma_f32_16x16x32_bf16(l.v, bh, acc2, 0, 0, 0);
            acc2 = __builtin_amdgcn_mfma_f32_16x16x32_bf16(l.v, bl, acc2, 0, 0, 0);
        }
        #pragma unroll
        for (int r = 0; r < 4; ++r)
            G[(size_t)(row0 + rowb + r) * FOUT + w * 16 + colb] = acc2[r];
    }
}

// ---------- layer-2 aggregate + bias + softmax: 16-lane group x float4 per node ----------
__global__ __launch_bounds__(256) void k_agg2sm(
    const float* __restrict__ G, const int2* __restrict__ ep,
    const float* __restrict__ dinv, const int* __restrict__ off,
    const float* __restrict__ b2, float* __restrict__ out) {
    int q = threadIdx.x >> 4, l = threadIdx.x & 15;
    int n = (blockIdx.x << 4) + q;
    const float* gc = G + (l << 2);
    float ax = 0.f, ay = 0.f, az = 0.f, aw = 0.f;
    int p = off[n], p1 = off[n + 1];
    for (; p + 4 <= p1; p += 4) {
        int2 e0 = ep[p], e1 = ep[p + 1], e2 = ep[p + 2], e3 = ep[p + 3];
        float4 v0 = *(const float4*)(gc + ((size_t)e0.x << 6));
        float4 v1 = *(const float4*)(gc + ((size_t)e1.x << 6));
        float4 v2 = *(const float4*)(gc + ((size_t)e2.x << 6));
        float4 v3 = *(const float4*)(gc + ((size_t)e3.x << 6));
        float c0 = __int_as_float(e0.y), c1 = __int_as_float(e1.y);
        float c2 = __int_as_float(e2.y), c3 = __int_as_float(e3.y);
        ax += c0 * v0.x + c1 * v1.x + c2 * v2.x + c3 * v3.x;
        ay += c0 * v0.y + c1 * v1.y + c2 * v2.y + c3 * v3.y;
        az += c0 * v0.z + c1 * v1.z + c2 * v2.z + c3 * v3.z;
        aw += c0 * v0.w + c1 * v1.w + c2 * v2.w + c3 * v3.w;
    }
    for (; p < p1; ++p) {
        int2 e = ep[p];
        float4 v = *(const float4*)(gc + ((size_t)e.x << 6));
        float c = __int_as_float(e.y);
        ax += c * v.x; ay += c * v.y; az += c * v.z; aw += c * v.w;
    }
    float dn = dinv[n];
    float s2 = dn * dn;
    float4 gv = *(const float4*)(gc + ((size_t)n << 6));
    float4 bv = *(const float4*)&b2[l << 2];
    ax += s2 * gv.x + bv.x; ay += s2 * gv.y + bv.y;
    az += s2 * gv.z + bv.z; aw += s2 * gv.w + bv.w;

    float m = fmaxf(fmaxf(ax, ay), fmaxf(az, aw));
    #pragma unroll
    for (int d = 8; d; d >>= 1) m = fmaxf(m, __shfl_xor(m, d, 16));
    float ex = __expf(ax - m), ey = __expf(ay - m), ez = __expf(az - m), ew_ = __expf(aw - m);
    float s = ex + ey + ez + ew_;
    #pragma unroll
    for (int d = 8; d; d >>= 1) s += __shfl_xor(s, d, 16);
    float inv = 1.0f / s;
    *(float4*)&out[((size_t)n << 6) + (l << 2)] =
        make_float4(ex * inv, ey * inv, ez * inv, ew_ * inv);
}

extern "C" void kernel_launch(void* const* d_in, const int* in_sizes, int n_in,
                              void* d_out, int out_size, void* d_ws, size_t ws_size,
                              hipStream_t stream) {
    const float* x  = (const float*)d_in[0];
    const int*   ei = (const int*)d_in[1];     // [2, NE]
    const float* ew = (const float*)d_in[2];
    // d_in[3..6] = W_gat, att_src, att_dst, b_gat — DEAD in the reference.
    const float* W1 = (const float*)d_in[7];
    const float* b1 = (const float*)d_in[8];
    const float* W2 = (const float*)d_in[9];
    const float* b2 = (const float*)d_in[10];

    const int* srcv = ei;
    const int* dstv = ei + NE;

    char* ws = (char*)d_ws;
    size_t o = 0;
    auto alloc = [&](size_t bytes) {
        void* p = ws + o;
        o = (o + bytes + 255) & ~(size_t)255;
        return p;
    };
    float* deg  = (float*)alloc(NN * sizeof(float));
    float* dinv = (float*)alloc(NN * sizeof(float));
    int*   cnt  = (int*)alloc(NN * sizeof(int));
    int*   off  = (int*)alloc((NN + 1) * sizeof(int));
    int*   bsum = (int*)alloc(32 * sizeof(int));
    int2*  ep   = (int2*)alloc((size_t)NE * sizeof(int2));
    float* A    = (float*)alloc((size_t)NN * FIN * sizeof(float));
    float* G    = (float*)alloc((size_t)NN * FOUT * sizeof(float));
    unsigned short* W1h = (unsigned short*)alloc(FIN * FHID * sizeof(unsigned short));
    unsigned short* W1l = (unsigned short*)alloc(FIN * FHID * sizeof(unsigned short));
    unsigned short* W2h = (unsigned short*)alloc(FHID * FOUT * sizeof(unsigned short));
    unsigned short* W2l = (unsigned short*)alloc(FHID * FOUT * sizeof(unsigned short));

    k_init   <<<(NN + 255) / 256, 256, 0, stream>>>(deg, cnt);
    k_deg    <<<(NE + 255) / 256, 256, 0, stream>>>(dstv, ew, deg, cnt);
    k_wpack  <<<16, 256, 0, stream>>>(W1, FIN, FHID, W1h, W1l);
    k_wpack  <<<8,  256, 0, stream>>>(W2, FHID, FOUT, W2h, W2l);
    k_scan1  <<<20, 1024, 0, stream>>>(cnt, deg, dinv, off, bsum);
    k_scan2  <<<1, 64, 0, stream>>>(bsum);
    k_scan3  <<<20, 1024, 0, stream>>>(off, bsum, cnt);
    k_scatter<<<(NE + 255) / 256, 256, 0, stream>>>(srcv, dstv, ew, dinv, off, cnt, ep);
    k_aggx   <<<NN / 8, 256, 0, stream>>>(x, ep, dinv, off, A);
    k_mlp    <<<NN / 16, 256, 0, stream>>>(A, W1h, W1l, b1, W2h, W2l, G);
    k_agg2sm <<<NN / 16, 256, 0, stream>>>(G, ep, dinv, off, b2, (float*)d_out);
}